// Round 1
// baseline (600.719 us; speedup 1.0000x reference)
//
#include <hip/hip_runtime.h>
#include <math.h>

#define T_STEPS 24
#define BATCH   128
#define DGI     256
#define DHI     512
#define S_ITERS 3
#define LAMBDA  0.95f
#define ETA     0.5f
#define EPS_A   1e-6f
#define LN_EPS  1e-5f
#define EPS_N   1e-6f
#define HIST_MAX 23   // at most T-1 stored rank-1 terms

// Tiled transpose: dst[c*R + r] = src[r*C + c].  R,C multiples of 32.
__global__ void transpose_k(const float* __restrict__ src, float* __restrict__ dst,
                            int R, int C) {
    __shared__ float tile[32][33];
    const int tx = threadIdx.x & 31;
    const int ty = threadIdx.x >> 5;          // 0..7 (256 threads)
    const int c0 = blockIdx.x * 32;
    const int r0 = blockIdx.y * 32;
    #pragma unroll
    for (int i = 0; i < 32; i += 8) {
        tile[ty + i][tx] = src[(size_t)(r0 + ty + i) * C + (c0 + tx)];
    }
    __syncthreads();
    #pragma unroll
    for (int i = 0; i < 32; i += 8) {
        dst[(size_t)(c0 + ty + i) * R + (r0 + tx)] = tile[tx][ty + i];
    }
}

// One block per batch element; 512 threads; thread i owns state index i.
// WT=true: Wh/Wg are pre-transposed (j-major) for coalesced loads.
template<bool WT>
__global__ __launch_bounds__(512)
void corernn_kernel(const float* __restrict__ z_seq,
                    const float* __restrict__ Wh,
                    const float* __restrict__ Wg,
                    const float* __restrict__ b_h,
                    const float* __restrict__ gamma,
                    const float* __restrict__ beta,
                    const float* __restrict__ alpha_fw,
                    float* __restrict__ out) {
    __shared__ __align__(16) float sh_hist[HIST_MAX][DHI]; // stored h_s vectors
    __shared__ __align__(16) float sh_hs[DHI];             // current h_s (and carry h)
    __shared__ __align__(16) float sh_z[DGI];
    __shared__ float sh_coef[HIST_MAX + 1];                // eta/hn2 * lambda^age
    __shared__ float sh_wdot[HIST_MAX + 1];                // coef[s] * (hist_s . h_s)
    __shared__ float sh_red[8 * 3];
    __shared__ float sh_bcast[4];

    const int tid  = threadIdx.x;
    const int lane = tid & 63;
    const int wave = tid >> 6;
    const int b    = blockIdx.x;

    const float bh_r = b_h[tid];
    const float g_r  = gamma[tid];
    const float bt_r = beta[tid];

    // k = compute_k(alpha_fw[0]); note softplus(|a|) serves both branches
    float kpow;
    {
        const float a  = alpha_fw[0];
        const float ax = fabsf(a);
        const float sp = (ax > 20.f) ? ax : log1pf(expf(ax));
        kpow = (a >= 0.f) ? (1.f + sp) : (1.f / (1.f + sp));
    }

    sh_hs[tid] = 0.f;   // h0 = 0
    float hs_i = 0.f;

    for (int t = 0; t < T_STEPS; ++t) {
        // stage z_t for this batch row
        if (tid < DGI) sh_z[tid] = z_seq[((size_t)t * BATCH + b) * DGI + tid];
        __syncthreads();   // covers z write + prev-step hist/coef/hs writes

        // ---- GEMV: h_base[i] = b_h[i] + sum_j Wh[i][j] h[j] + sum_j Wg[i][j] z[j]
        float acc = bh_r;
        {
            const float4* h4p = reinterpret_cast<const float4*>(sh_hs);
            #pragma unroll 4
            for (int j4 = 0; j4 < DHI / 4; ++j4) {
                const float4 h4 = h4p[j4];
                const int j = j4 * 4;
                if (WT) {
                    const int base = j * DHI + tid;
                    acc = fmaf(Wh[base        ], h4.x, acc);
                    acc = fmaf(Wh[base +   DHI], h4.y, acc);
                    acc = fmaf(Wh[base + 2*DHI], h4.z, acc);
                    acc = fmaf(Wh[base + 3*DHI], h4.w, acc);
                } else {
                    const int base = tid * DHI + j;
                    acc = fmaf(Wh[base    ], h4.x, acc);
                    acc = fmaf(Wh[base + 1], h4.y, acc);
                    acc = fmaf(Wh[base + 2], h4.z, acc);
                    acc = fmaf(Wh[base + 3], h4.w, acc);
                }
            }
            const float4* z4p = reinterpret_cast<const float4*>(sh_z);
            #pragma unroll 4
            for (int j4 = 0; j4 < DGI / 4; ++j4) {
                const float4 h4 = z4p[j4];
                const int j = j4 * 4;
                if (WT) {
                    const int base = j * DHI + tid;
                    acc = fmaf(Wg[base        ], h4.x, acc);
                    acc = fmaf(Wg[base +   DHI], h4.y, acc);
                    acc = fmaf(Wg[base + 2*DHI], h4.z, acc);
                    acc = fmaf(Wg[base + 3*DHI], h4.w, acc);
                } else {
                    const int base = tid * DGI + j;
                    acc = fmaf(Wg[base    ], h4.x, acc);
                    acc = fmaf(Wg[base + 1], h4.y, acc);
                    acc = fmaf(Wg[base + 2], h4.z, acc);
                    acc = fmaf(Wg[base + 3], h4.w, acc);
                }
            }
        }
        const float hbase_i = acc;
        __syncthreads();                    // all reads of old sh_hs done
        hs_i = fmaxf(hbase_i, 0.f);
        sh_hs[tid] = hs_i;
        __syncthreads();

        // ---- inner associative-memory iterations
        for (int it = 0; it < S_ITERS; ++it) {
            // scaled dots: wdot[s] = coef[s] * (hist_s . h_s); waves split s
            for (int s = wave; s < t; s += 8) {
                float p = 0.f;
                #pragma unroll
                for (int q = 0; q < 8; ++q) {
                    const int idx = lane + 64 * q;
                    p += sh_hist[s][idx] * sh_hs[idx];
                }
                #pragma unroll
                for (int off = 32; off > 0; off >>= 1) p += __shfl_xor(p, off, 64);
                if (lane == 0) sh_wdot[s] = p * sh_coef[s];
            }
            __syncthreads();

            // Ah[i] = sum_s wdot[s] * hist_s[i]
            float Ah = 0.f;
            for (int s = 0; s < t; ++s) Ah = fmaf(sh_wdot[s], sh_hist[s][tid], Ah);

            // block-reduce {hs.Ah, |hs|^2, |Ah|^2}
            float p0 = hs_i * Ah, p1 = hs_i * hs_i, p2 = Ah * Ah;
            #pragma unroll
            for (int off = 32; off > 0; off >>= 1) {
                p0 += __shfl_xor(p0, off, 64);
                p1 += __shfl_xor(p1, off, 64);
                p2 += __shfl_xor(p2, off, 64);
            }
            if (lane == 0) {
                sh_red[wave * 3 + 0] = p0;
                sh_red[wave * 3 + 1] = p1;
                sh_red[wave * 3 + 2] = p2;
            }
            __syncthreads();
            if (tid < 3) {
                float ssum = 0.f;
                #pragma unroll
                for (int w = 0; w < 8; ++w) ssum += sh_red[w * 3 + tid];
                sh_bcast[tid] = ssum;
            }
            __syncthreads();

            const float dot = sh_bcast[0];
            const float n1  = fmaxf(sqrtf(sh_bcast[1]), EPS_N);
            const float n2  = fmaxf(sqrtf(sh_bcast[2]), EPS_N);
            float R = dot / (n1 * n2);
            R = fminf(fmaxf(R, 0.f), 1.f);
            const float alpha = 1.f - powf(1.f - R, kpow);
            const float y = (1.f - alpha * alpha) * hbase_i + alpha * Ah;

            // LayerNorm stats
            float q0 = y, q1 = y * y;
            #pragma unroll
            for (int off = 32; off > 0; off >>= 1) {
                q0 += __shfl_xor(q0, off, 64);
                q1 += __shfl_xor(q1, off, 64);
            }
            if (lane == 0) { sh_red[wave * 3 + 0] = q0; sh_red[wave * 3 + 1] = q1; }
            __syncthreads();
            if (tid < 2) {
                float ssum = 0.f;
                #pragma unroll
                for (int w = 0; w < 8; ++w) ssum += sh_red[w * 3 + tid];
                sh_bcast[tid] = ssum;
            }
            __syncthreads();
            const float mean = sh_bcast[0] * (1.f / DHI);
            const float var  = sh_bcast[1] * (1.f / DHI) - mean * mean;
            const float rstd = rsqrtf(var + LN_EPS);
            hs_i = fmaxf(fmaf((y - mean) * rstd, g_r, bt_r), 0.f);
            sh_hs[tid] = hs_i;
            __syncthreads();
        }

        if (t < T_STEPS - 1) {
            // hn2 = |h_s|^2 + eps, then append rank-1 term and decay old coefs
            float p = hs_i * hs_i;
            #pragma unroll
            for (int off = 32; off > 0; off >>= 1) p += __shfl_xor(p, off, 64);
            if (lane == 0) sh_red[wave * 3] = p;
            __syncthreads();
            if (tid == 0) {
                float ssum = 0.f;
                #pragma unroll
                for (int w = 0; w < 8; ++w) ssum += sh_red[w * 3];
                sh_bcast[0] = ssum + EPS_A;
            }
            __syncthreads();
            const float hn2 = sh_bcast[0];
            if (tid < t)  sh_coef[tid] *= LAMBDA;   // age existing terms
            if (tid == t) sh_coef[t] = ETA / hn2;   // insert new term
            sh_hist[t][tid] = hs_i;
            // next timestep's first __syncthreads makes these visible
        } else {
            out[(size_t)b * DHI + tid] = hs_i;
        }
    }
}

extern "C" void kernel_launch(void* const* d_in, const int* in_sizes, int n_in,
                              void* d_out, int out_size, void* d_ws, size_t ws_size,
                              hipStream_t stream) {
    const float* z_seq    = (const float*)d_in[0];
    const float* W_h      = (const float*)d_in[1];
    const float* W_g      = (const float*)d_in[2];
    const float* b_h      = (const float*)d_in[3];
    const float* gamma    = (const float*)d_in[4];
    const float* beta     = (const float*)d_in[5];
    const float* alpha_fw = (const float*)d_in[6];
    float* out = (float*)d_out;

    const size_t needed = (size_t)(DHI * DHI + DGI * DHI) * sizeof(float);
    if (ws_size >= needed) {
        float* WhT = (float*)d_ws;            // [DHI][DHI] j-major
        float* WgT = WhT + (size_t)DHI * DHI; // [DGI][DHI] j-major
        transpose_k<<<dim3(DHI / 32, DHI / 32), 256, 0, stream>>>(W_h, WhT, DHI, DHI);
        transpose_k<<<dim3(DGI / 32, DHI / 32), 256, 0, stream>>>(W_g, WgT, DHI, DGI);
        corernn_kernel<true><<<BATCH, DHI, 0, stream>>>(z_seq, WhT, WgT, b_h, gamma,
                                                        beta, alpha_fw, out);
    } else {
        corernn_kernel<false><<<BATCH, DHI, 0, stream>>>(z_seq, W_h, W_g, b_h, gamma,
                                                         beta, alpha_fw, out);
    }
}